// Round 1
// baseline (534.507 us; speedup 1.0000x reference)
//
#include <hip/hip_runtime.h>

// OrbitalAEVComputer on MI355X.
// Per (conf,atom): 21 f32 coeffs -> 1744 f32 outputs:
//   [0,144)    s_aev:      exp(-16*(s_i - shfS_k)^2),           i<9,  k<16
//   [144,208)  radial_aev: exp(-8*(|p_i| - shfR_k)^2),          i<4,  k<16
//   [208,1744) angular:    2^-7*((1+cos(ang_p - Th_t))/2)^8 * exp(-8*(av_p - shfA_a)^2)
//              flat index p*256 + t*16 + a,  p<6 pairs, t<16, a<16
// cos(ang - Th) expanded as c*cosTh + sqrt(1-c^2)*sinTh  (ang in [0,pi]) -> no arccos.
// Write-BW bound: 457 MB out, 5.5 MB in. One float4 per thread, nontemporal.

namespace {

typedef float f4 __attribute__((ext_vector_type(4)));

constexpr int kPerAtom = 9 * 16 + 4 * 16 + 6 * 16 * 16;  // 1744 floats
constexpr int kQ = kPerAtom / 4;                          // 436 float4 per atom

// cos/sin of Th_k = k*pi/15, k = 0..15 (reference: jnp.linspace(0, pi, 16))
__device__ __constant__ float kCosT[16] = {
     1.0f,          0.97814760f,  0.91354546f,  0.80901699f,
     0.66913061f,   0.5f,         0.30901699f,  0.10452846f,
    -0.10452846f,  -0.30901699f, -0.5f,        -0.66913061f,
    -0.80901699f,  -0.91354546f, -0.97814760f, -1.0f };
__device__ __constant__ float kSinT[16] = {
     0.0f,          0.20791169f,  0.40673664f,  0.58778525f,
     0.74314483f,   0.86602540f,  0.95105652f,  0.99452190f,
     0.99452190f,   0.95105652f,  0.86602540f,  0.74314483f,
     0.58778525f,   0.40673664f,  0.20791169f,  0.0f };

__global__ __launch_bounds__(448) void aev_kernel(
    const float* __restrict__ coeff, float* __restrict__ out)
{
    const int atom = blockIdx.x;                       // conf*64 + atom, 0..65535
    const float* __restrict__ c = coeff + (long long)atom * 21;
    f4* __restrict__ outv =
        reinterpret_cast<f4*>(out + (long long)atom * kPerAtom);

    const int q = threadIdx.x;                         // one float4 per thread
    if (q >= kQ) return;

    float r[4];

    if (q < 36) {
        // ---- s_aev: 9 coeffs x 16 shifts ----
        const int e  = q << 2;
        const int i  = e >> 4;       // which s coeff
        const int k0 = e & 15;       // shift base (0,4,8,12)
        const float s = c[i];
#pragma unroll
        for (int u = 0; u < 4; ++u) {
            const float shf = -4.0f + (float)(k0 + u) * (8.0f / 15.0f);
            const float d = s - shf;
            r[u] = __expf(-16.0f * d * d);
        }
    } else if (q < 52) {
        // ---- radial_aev: 4 p-norms x 16 shifts ----
        const int e  = (q - 36) << 2;
        const int i  = e >> 4;
        const int k0 = e & 15;
        const float px = c[9 + 3 * i], py = c[10 + 3 * i], pz = c[11 + 3 * i];
        const float n = sqrtf(px * px + py * py + pz * pz);
#pragma unroll
        for (int u = 0; u < 4; ++u) {
            const float shf = (float)(k0 + u) * (4.0f / 15.0f);
            const float d = n - shf;
            r[u] = __expf(-8.0f * d * d);
        }
    } else {
        // ---- angular: 6 pairs x 16 theta x 16 dist ----
        const int e  = (q - 52) << 2;
        const int p  = e >> 8;              // pair
        const int tt = (e >> 4) & 15;       // theta index
        const int a0 = e & 15;              // dist-shift base (0,4,8,12)
        const int IU[6] = {0, 0, 0, 1, 1, 2};
        const int JU[6] = {1, 2, 3, 2, 3, 3};
        const int i = IU[p], j = JU[p];
        const float ax = c[9 + 3 * i], ay = c[10 + 3 * i], az = c[11 + 3 * i];
        const float bx = c[9 + 3 * j], by = c[10 + 3 * j], bz = c[11 + 3 * j];
        const float na = sqrtf(ax * ax + ay * ay + az * az);
        const float nb = sqrtf(bx * bx + by * by + bz * bz);
        const bool ma = fabsf(ax) < 1e-12f && fabsf(ay) < 1e-12f && fabsf(az) < 1e-12f;
        const bool mb = fabsf(bx) < 1e-12f && fabsf(by) < 1e-12f && fabsf(bz) < 1e-12f;
        float cc = (ma || mb) ? 0.0f : (ax * bx + ay * by + az * bz) / (na * nb);
        cc = fminf(0.9999f, fmaxf(-0.9999f, cc));
        const float sn = sqrtf(1.0f - cc * cc);          // sin(ang) >= 0 on [0,pi]
        const float av = 0.5f * (na + nb);
        const float ct = cc * kCosT[tt] + sn * kSinT[tt]; // cos(ang - Th_tt)
        const float t  = 0.5f * (1.0f + ct);
        const float t2 = t * t, t4 = t2 * t2;
        const float ft = 0.0078125f * (t4 * t4);          // 2^(1-8) * t^8
#pragma unroll
        for (int u = 0; u < 4; ++u) {
            const float shf = (float)(a0 + u) * (4.0f / 15.0f);
            const float d = av - shf;
            r[u] = ft * __expf(-8.0f * d * d);
        }
    }

    const f4 v = {r[0], r[1], r[2], r[3]};
    __builtin_nontemporal_store(v, &outv[q]);   // write-once, >L2: bypass
}

}  // namespace

extern "C" void kernel_launch(void* const* d_in, const int* in_sizes, int n_in,
                              void* d_out, int out_size, void* d_ws, size_t ws_size,
                              hipStream_t stream) {
    const float* coeff = (const float*)d_in[0];   // (1024, 64, 21) f32
    // d_in[1] (normalization_library) and d_in[2] (species) are unused by _forward.
    float* out = (float*)d_out;                   // (1024, 64, 1744) f32
    const int nblocks = 1024 * 64;                // one block per (conf, atom)
    aev_kernel<<<dim3(nblocks), dim3(448), 0, stream>>>(coeff, out);
}

// Round 2
// 514.847 us; speedup vs baseline: 1.0382x; 1.0382x over previous
//
#include <hip/hip_runtime.h>

// OrbitalAEVComputer on MI355X (gfx950).
// Per (conf,atom): 21 f32 coeffs -> 1744 f32 outputs:
//   [0,144)    s_aev:      exp(-16*(s_i - shfS_k)^2),           i<9,  k<16
//   [144,208)  radial_aev: exp(-8*(|p_i| - shfR_k)^2),          i<4,  k<16
//   [208,1744) angular:    2^-7*((1+cos(ang_p - Th_t))/2)^8 * exp(-8*(av_p - shfA_a)^2)
//              flat index p*256 + t*16 + a,  p<6 pairs, t<16, a<16
//
// Angular factorizes: out[p,t,a] = ft[p,t] * fd[p,a].  Build both 96-entry
// tables once per atom in LDS, then 384 writer threads do 2 LDS reads + mult.
// cos(ang - Th) = cc*cos(Th) + sqrt(1-cc^2)*sin(Th)  (ang in [0,pi]) -> no arccos.
// Approx intrinsics (v_rsq/v_sqrt/v_exp) are fine: harness tolerance >= 2^-8.
// Write-BW bound: 457 MB out, 5.5 MB in -> target ~75-100 us @ 6.3 TB/s.

namespace {

typedef float f4 __attribute__((ext_vector_type(4)));

constexpr int kPerAtom = 1744;
constexpr int kQ = kPerAtom / 4;   // 436 float4 per atom
constexpr float kPi = 3.14159265358979323846f;

__global__ __launch_bounds__(448) void aev_kernel(
    const float* __restrict__ coeff, float* __restrict__ out)
{
    __shared__ float sCC[6], sSN[6], sAV[6];
    __shared__ float sFT[96];   // [pair][theta]
    __shared__ float sFD[96];   // [pair][dist]

    const int atom = blockIdx.x;                       // conf*64 + atom
    const float* __restrict__ c = coeff + (long long)atom * 21;
    const int q = threadIdx.x;

    // ---- Phase A: 6 threads compute per-pair scalars ----
    if (q < 6) {
        const int p = q;
        const int i = (p < 3) ? 0 : ((p < 5) ? 1 : 2);
        const int j = (p < 3) ? (p + 1) : ((p < 5) ? (p - 1) : 3);
        const float ax = c[9 + 3 * i], ay = c[10 + 3 * i], az = c[11 + 3 * i];
        const float bx = c[9 + 3 * j], by = c[10 + 3 * j], bz = c[11 + 3 * j];
        const float na2 = ax * ax + ay * ay + az * az;
        const float nb2 = bx * bx + by * by + bz * bz;
        const float dot = ax * bx + ay * by + az * bz;
        // zero-vector guard (reference: p_hat = 0 -> cos = 0)
        const float ia = (na2 > 1e-24f) ? __builtin_amdgcn_rsqf(na2) : 0.0f;
        const float ib = (nb2 > 1e-24f) ? __builtin_amdgcn_rsqf(nb2) : 0.0f;
        float cc = dot * ia * ib;
        cc = fminf(0.9999f, fmaxf(-0.9999f, cc));
        sCC[p] = cc;
        sSN[p] = __builtin_amdgcn_sqrtf(1.0f - cc * cc);  // sin(ang) >= 0
        sAV[p] = 0.5f * (na2 * ia + nb2 * ib);            // (|a|+|b|)/2
    }
    __syncthreads();

    // ---- Phase B: build the two 96-entry tables ----
    if (q < 96) {                       // ft[p][t]
        const int p = q >> 4, t = q & 15;
        const float th = (float)t * (kPi / 15.0f);
        const float ct = __cosf(th), st = __sinf(th);
        const float x = 0.5f * (1.0f + sCC[p] * ct + sSN[p] * st);
        const float x2 = x * x, x4 = x2 * x2;
        sFT[q] = 0.0078125f * (x4 * x4);                  // 2^(1-8) * x^8
    } else if (q < 192) {               // fd[p][a]
        const int idx = q - 96;
        const int p = idx >> 4, a = idx & 15;
        const float d = sAV[p] - (float)a * (4.0f / 15.0f);
        sFD[idx] = __expf(-8.0f * d * d);
    }
    __syncthreads();

    // ---- Phase C: 436 threads each write one float4, coalesced ----
    float r[4];
    if (q < 36) {
        // s_aev: 9 coeffs x 16 shifts
        const int i  = q >> 2;
        const int k0 = (q & 3) << 2;
        const float s = c[i];
#pragma unroll
        for (int u = 0; u < 4; ++u) {
            const float d = s - (-4.0f + (float)(k0 + u) * (8.0f / 15.0f));
            r[u] = __expf(-16.0f * d * d);
        }
    } else if (q < 52) {
        // radial_aev: 4 p-norms x 16 shifts
        const int i  = (q - 36) >> 2;
        const int k0 = ((q - 36) & 3) << 2;
        const float px = c[9 + 3 * i], py = c[10 + 3 * i], pz = c[11 + 3 * i];
        const float n = __builtin_amdgcn_sqrtf(px * px + py * py + pz * pz);
#pragma unroll
        for (int u = 0; u < 4; ++u) {
            const float d = n - (float)(k0 + u) * (4.0f / 15.0f);
            r[u] = __expf(-8.0f * d * d);
        }
    } else if (q < kQ) {
        // angular: ft[p,t] * fd[p,a0+u]
        const int e  = (q - 52) << 2;
        const int p  = e >> 8;
        const int tt = (e >> 4) & 15;
        const int a0 = e & 15;
        const float ft = sFT[p * 16 + tt];
        const f4 fd = *reinterpret_cast<const f4*>(&sFD[p * 16 + a0]);
#pragma unroll
        for (int u = 0; u < 4; ++u) r[u] = ft * fd[u];
    }

    if (q < kQ) {
        f4* __restrict__ outv = reinterpret_cast<f4*>(out + (long long)atom * kPerAtom);
        const f4 v = {r[0], r[1], r[2], r[3]};
        outv[q] = v;
    }
}

}  // namespace

extern "C" void kernel_launch(void* const* d_in, const int* in_sizes, int n_in,
                              void* d_out, int out_size, void* d_ws, size_t ws_size,
                              hipStream_t stream) {
    const float* coeff = (const float*)d_in[0];   // (1024, 64, 21) f32
    // d_in[1] (normalization_library) and d_in[2] (species) are dead in _forward.
    float* out = (float*)d_out;                   // (1024, 64, 1744) f32
    aev_kernel<<<dim3(1024 * 64), dim3(448), 0, stream>>>(coeff, out);
}

// Round 4
// 460.532 us; speedup vs baseline: 1.1606x; 1.1179x over previous
//
#include <hip/hip_runtime.h>

// OrbitalAEVComputer on MI355X (gfx950) — v3: one WAVE per atom, no barriers.
// (Resubmission: Round-3 bench failed with GPUAcquisitionTimeout; no data.)
//
// Per (conf,atom): 21 f32 coeffs -> 1744 f32 outputs:
//   [0,144)    s_aev:      exp(-16*(s_i - shfS_k)^2),          i<9,  k<16
//   [144,208)  radial_aev: exp(-8*(|p_i| - shfR_k)^2),         i<4,  k<16
//   [208,1744) angular:    2^-7*((1+cos(ang_p - Th_t))/2)^8 * exp(-8*(av_p - shfA_a)^2)
//              flat p*256 + t*16 + a,  p<6 pairs, t<16, a<16  (separable: ft[p,t]*fd[p,a])
//
// Round-2 lesson: 65536 tiny blocks (1 store/thread, 2 __syncthreads) were
// block-throughput-bound (~225 us device), not VALU-bound. This version copies
// the fill kernel's shape: few blocks, deep per-wave store loops. Each wave
// owns an atom: builds ft/fd tables in its private LDS slice (wave-synchronous,
// s_waitcnt lgkmcnt(0) fence only), then 7 coalesced 1KB wave-stores.
// cos(ang-Th) = cc*cosTh + sqrt(1-cc^2)*sinTh (ang in [0,pi]) -> no arccos.
// Write-BW bound: 457 MB out / ~6.3 TB/s -> ~75 us target.

namespace {

typedef float f4 __attribute__((ext_vector_type(4)));

constexpr int kPerAtom  = 1744;
constexpr int kQ        = kPerAtom / 4;       // 436 float4 per atom
constexpr int kAtoms    = 1024 * 64;          // 65536
constexpr int kBlocks   = 2048;
constexpr int kWavesTot = kBlocks * 4;        // 8192 waves, 8 atoms each
constexpr float kPi = 3.14159265358979323846f;

// Wave-synchronous LDS fence: all prior ds_writes visible to this wave's
// subsequent ds_reads; "memory" stops compiler reordering across it.
__device__ inline void wave_lds_fence() {
    asm volatile("s_waitcnt lgkmcnt(0)" ::: "memory");
}

__global__ __launch_bounds__(256) void aev_kernel(
    const float* __restrict__ coeff, float* __restrict__ out)
{
    // Per-wave private table slice (no cross-wave sharing -> no __syncthreads):
    //   [0..95]    ft[p][t]      [96..191]  fd[p][a]
    //   [192..200] s0..s8        [201..204] |p_i|
    //   [205..210] cc[p]         [211..216] sn[p]        [217..222] av[p]
    __shared__ float tab[4][224];               // 224*4B = 896 B/wave (16B-aligned rows)

    const int lane = threadIdx.x & 63;
    const int wid  = (blockIdx.x << 2) | (threadIdx.x >> 6);
    float* __restrict__ t = tab[threadIdx.x >> 6];

    for (int atom = wid; atom < kAtoms; atom += kWavesTot) {
        const float* __restrict__ ca = coeff + (long long)atom * 21;

        // ---- Phase 1: per-atom scalars (lanes 0..18) ----
        if (lane < 6) {
            const int p = lane;
            const int i = (p < 3) ? 0 : ((p < 5) ? 1 : 2);
            const int j = (p < 3) ? (p + 1) : ((p < 5) ? (p - 1) : 3);
            const float ax = ca[9 + 3 * i], ay = ca[10 + 3 * i], az = ca[11 + 3 * i];
            const float bx = ca[9 + 3 * j], by = ca[10 + 3 * j], bz = ca[11 + 3 * j];
            const float na2 = ax * ax + ay * ay + az * az;
            const float nb2 = bx * bx + by * by + bz * bz;
            const float dot = ax * bx + ay * by + az * bz;
            // reference zero-mask: p_hat = 0 for (near-)zero vectors
            const float ia = (na2 > 1e-24f) ? __builtin_amdgcn_rsqf(na2) : 0.0f;
            const float ib = (nb2 > 1e-24f) ? __builtin_amdgcn_rsqf(nb2) : 0.0f;
            float cc = dot * ia * ib;
            cc = fminf(0.9999f, fmaxf(-0.9999f, cc));
            t[205 + p] = cc;
            t[211 + p] = __builtin_amdgcn_sqrtf(1.0f - cc * cc);  // sin >= 0 on [0,pi]
            t[217 + p] = 0.5f * (na2 * ia + nb2 * ib);            // (|a|+|b|)/2
        } else if (lane < 10) {
            const int i = lane - 6;
            const float px = ca[9 + 3 * i], py = ca[10 + 3 * i], pz = ca[11 + 3 * i];
            t[201 + i] = __builtin_amdgcn_sqrtf(px * px + py * py + pz * pz);
        } else if (lane < 19) {
            t[192 + (lane - 10)] = ca[lane - 10];
        }
        wave_lds_fence();

        // ---- Phase 2: build ft[96] + fd[96] (3 rounds x 64 lanes) ----
#pragma unroll
        for (int r = 0; r < 3; ++r) {
            const int k = r * 64 + lane;          // 0..191
            float v;
            if (k < 96) {                          // ft[p][tt]
                const int p = k >> 4, tt = k & 15;
                const float th = (float)tt * (kPi / 15.0f);
                const float x = 0.5f * (1.0f + t[205 + p] * __cosf(th)
                                             + t[211 + p] * __sinf(th));
                const float x2 = x * x, x4 = x2 * x2;
                v = 0.0078125f * (x4 * x4);        // 2^(1-8) * x^8
            } else {                               // fd[p][a]
                const int m = k - 96;
                const int p = m >> 4, a = m & 15;
                const float d = t[217 + p] - (float)a * (4.0f / 15.0f);
                v = __expf(-8.0f * d * d);
            }
            t[k] = v;
        }
        wave_lds_fence();

        // ---- Phase 3: 7 coalesced 1KB wave-stores ----
        f4* __restrict__ outv = reinterpret_cast<f4*>(out + (long long)atom * kPerAtom);
#pragma unroll
        for (int r = 0; r < 7; ++r) {
            const int f = r * 64 + lane;
            if (f < kQ) {
                float rv[4];
                if (f < 36) {                      // s_aev
                    const int i = f >> 2, k0 = (f & 3) << 2;
                    const float s = t[192 + i];
#pragma unroll
                    for (int u = 0; u < 4; ++u) {
                        const float d = s - (-4.0f + (float)(k0 + u) * (8.0f / 15.0f));
                        rv[u] = __expf(-16.0f * d * d);
                    }
                } else if (f < 52) {               // radial
                    const int i = (f - 36) >> 2, k0 = ((f - 36) & 3) << 2;
                    const float n = t[201 + i];
#pragma unroll
                    for (int u = 0; u < 4; ++u) {
                        const float d = n - (float)(k0 + u) * (4.0f / 15.0f);
                        rv[u] = __expf(-8.0f * d * d);
                    }
                } else {                           // angular: ft[p,t] * fd[p,a0..a0+3]
                    const int e = (f - 52) << 2;
                    const int p = e >> 8, tt = (e >> 4) & 15, a0 = e & 15;
                    const float ftv = t[p * 16 + tt];
                    const f4 fdv = *reinterpret_cast<const f4*>(&t[96 + p * 16 + a0]);
#pragma unroll
                    for (int u = 0; u < 4; ++u) rv[u] = ftv * fdv[u];
                }
                const f4 v = {rv[0], rv[1], rv[2], rv[3]};
                outv[f] = v;
            }
        }
        // next atom reuses t[]: phase-1 writes are ordered behind this atom's
        // phase-3 reads by the next iteration's wave_lds_fence before any read.
        wave_lds_fence();
    }
}

}  // namespace

extern "C" void kernel_launch(void* const* d_in, const int* in_sizes, int n_in,
                              void* d_out, int out_size, void* d_ws, size_t ws_size,
                              hipStream_t stream) {
    const float* coeff = (const float*)d_in[0];   // (1024, 64, 21) f32
    // d_in[1] (normalization_library) and d_in[2] (species) are dead in _forward.
    float* out = (float*)d_out;                   // (1024, 64, 1744) f32
    aev_kernel<<<dim3(kBlocks), dim3(256), 0, stream>>>(coeff, out);
}